// Round 2
// baseline (196.425 us; speedup 1.0000x reference)
//
#include <hip/hip_runtime.h>

#define DIMC 64
#define KS 7
#define NTAP (KS*KS)      // 49
#define GCH 8             // channels per group
#define NG 8              // groups
#define CMID 32
#define PADD 3
#define HH 128
#define WW 128
#define PLANE (HH*WW)
#define TW 32
#define TH 8
#define TPX (TW+2*PADD)   // 38
#define TPY (TH+2*PADD)   // 14
#define NPIX (TPX*TPY)    // 532
#define CPAD 12

__global__ __launch_bounds__(256, 1)
void invol_fused_kernel(const float* __restrict__ x, const float* __restrict__ y,
                        const float* __restrict__ w1, const float* __restrict__ b1,
                        const float* __restrict__ w2, const float* __restrict__ b2,
                        float* __restrict__ out) {
    __shared__ float ytile[NPIX * CPAD];   // 25.5 KB

    const int tid = threadIdx.x;
    const int tx = tid & 31;
    const int ty = tid >> 5;
    const int bx = blockIdx.x, by = blockIdx.y, bz = blockIdx.z;
    const int gx = bx * TW + tx;
    const int gy = by * TH + ty;

    // ---- phase 0: mid[32] = w1 @ x(:,pixel) + b1 ----
    float xv[DIMC];
    const float* xp = x + ((size_t)(bz * DIMC) * HH + gy) * WW + gx;
    #pragma unroll
    for (int c = 0; c < DIMC; ++c) xv[c] = xp[c * PLANE];

    float mid[CMID];
    #pragma unroll
    for (int m = 0; m < CMID; ++m) {
        float a = b1[m];
        const float4* w1r = reinterpret_cast<const float4*>(w1 + m * DIMC);
        #pragma unroll
        for (int cq = 0; cq < DIMC / 4; ++cq) {
            float4 wv = w1r[cq];
            a = fmaf(wv.x, xv[4*cq+0], a);
            a = fmaf(wv.y, xv[4*cq+1], a);
            a = fmaf(wv.z, xv[4*cq+2], a);
            a = fmaf(wv.w, xv[4*cq+3], a);
        }
        mid[m] = a;
    }

    // ---- per-group: stage y tile, compute wt[49], involution ----
    for (int g = 0; g < NG; ++g) {
        __syncthreads();   // previous tile fully consumed
        // stage y halo tile for this group's 8 channels, zero-padded borders
        for (int i = tid; i < NPIX * GCH; i += 256) {
            int c = i / NPIX;
            int p = i - c * NPIX;
            int r = p / TPX;
            int col = p - r * TPX;
            int sy = by * TH + r - PADD;
            int sx = bx * TW + col - PADD;
            float v = 0.f;
            if (sy >= 0 && sy < HH && sx >= 0 && sx < WW)
                v = y[((size_t)(bz * DIMC + g * GCH + c) * HH + sy) * WW + sx];
            ytile[p * CPAD + c] = v;
        }
        __syncthreads();

        // wt[kk] = b2[g*49+kk] + sum_m w2[(g*49+kk)*32+m] * mid[m]
        float wt[NTAP];
        const float*  b2g = b2 + g * NTAP;
        const float4* w2g = reinterpret_cast<const float4*>(w2 + g * NTAP * CMID);
        #pragma unroll
        for (int kk = 0; kk < NTAP; ++kk) {
            float a = b2g[kk];
            #pragma unroll
            for (int mq = 0; mq < CMID / 4; ++mq) {
                float4 wv = w2g[kk * (CMID / 4) + mq];
                a = fmaf(wv.x, mid[4*mq+0], a);
                a = fmaf(wv.y, mid[4*mq+1], a);
                a = fmaf(wv.z, mid[4*mq+2], a);
                a = fmaf(wv.w, mid[4*mq+3], a);
            }
            wt[kk] = a;
        }

        // involution accumulate: 8 channels x 49 taps
        float acc[GCH];
        #pragma unroll
        for (int cc = 0; cc < GCH; ++cc) acc[cc] = 0.f;
        #pragma unroll
        for (int ky = 0; ky < KS; ++ky) {
            #pragma unroll
            for (int kx = 0; kx < KS; ++kx) {
                float wv = wt[ky * KS + kx];
                int pp = (ty + ky) * TPX + (tx + kx);
                const float4* yr = reinterpret_cast<const float4*>(&ytile[pp * CPAD]);
                float4 ya = yr[0];
                float4 yb = yr[1];
                acc[0] = fmaf(wv, ya.x, acc[0]);
                acc[1] = fmaf(wv, ya.y, acc[1]);
                acc[2] = fmaf(wv, ya.z, acc[2]);
                acc[3] = fmaf(wv, ya.w, acc[3]);
                acc[4] = fmaf(wv, yb.x, acc[4]);
                acc[5] = fmaf(wv, yb.y, acc[5]);
                acc[6] = fmaf(wv, yb.z, acc[6]);
                acc[7] = fmaf(wv, yb.w, acc[7]);
            }
        }

        float* op = out + ((size_t)(bz * DIMC + g * GCH) * HH + gy) * WW + gx;
        #pragma unroll
        for (int cc = 0; cc < GCH; ++cc) op[cc * PLANE] = acc[cc];
    }
}

extern "C" void kernel_launch(void* const* d_in, const int* in_sizes, int n_in,
                              void* d_out, int out_size, void* d_ws, size_t ws_size,
                              hipStream_t stream) {
    const float* x  = (const float*)d_in[0];
    const float* y  = (const float*)d_in[1];
    const float* w1 = (const float*)d_in[2];
    const float* b1 = (const float*)d_in[3];
    const float* w2 = (const float*)d_in[4];
    const float* b2 = (const float*)d_in[5];
    float* out = (float*)d_out;

    dim3 grid(WW / TW, HH / TH, 4);
    dim3 block(256);
    hipLaunchKernelGGL(invol_fused_kernel, grid, block, 0, stream,
                       x, y, w1, b1, w2, b2, out);
}